// Round 3
// baseline (242.113 us; speedup 1.0000x reference)
//
#include <hip/hip_runtime.h>

// MultiAttention fused pipeline for MI355X (gfx950).
// B=1, C=64, H=W=64 (N=4096), NH=8, DK=64, D=512.

#define LOG2E 1.442695040888963f

typedef __attribute__((ext_vector_type(8))) short bf16x8;
typedef __attribute__((ext_vector_type(4))) float f32x4;
typedef __attribute__((ext_vector_type(2))) float f32x2;
typedef __attribute__((ext_vector_type(4))) int i32x4;
typedef __attribute__((ext_vector_type(2))) int i32x2;
typedef __attribute__((ext_vector_type(4))) ushort u16x4;

__device__ __forceinline__ ushort f2bf(float x){
  uint u = __float_as_uint(x);
  u += 0x7fffu + ((u >> 16) & 1u);   // round-to-nearest-even
  return (ushort)(u >> 16);
}
__device__ __forceinline__ float bf2f(ushort h){
  return __uint_as_float(((uint)h) << 16);
}
__device__ __forceinline__ float gelu_(float x){
  return 0.5f * x * (1.0f + erff(x * 0.70710678118654752f));
}
__device__ __forceinline__ float sigmoid_(float x){
  return 1.0f / (1.0f + __expf(-x));
}
__device__ __forceinline__ float exp2_(float x){
  float r; asm("v_exp_f32 %0, %1" : "=v"(r) : "v"(x)); return r;
}
__device__ __forceinline__ int cvtpk(float lo, float hi){
  int r; asm("v_cvt_pk_bf16_f32 %0, %1, %2" : "=v"(r) : "v"(lo), "v"(hi)); return r;
}
__device__ __forceinline__ bf16x8 packf8(const float* s){
  f32x4 x0 = *(const f32x4*)s;
  f32x4 x1 = *(const f32x4*)(s+4);
  union{ i32x4 i; bf16x8 v; } u;
  u.i[0]=cvtpk(x0[0],x0[1]); u.i[1]=cvtpk(x0[2],x0[3]);
  u.i[2]=cvtpk(x1[0],x1[1]); u.i[3]=cvtpk(x1[2],x1[3]);
  return u.v;
}

// ---------------- K2: QKV projection (MFMA) + cosine norm for q,k ----------
// grid (256, 3): 16 rows/block, z = 0:q 1:k 2:v. block 256 = 4 waves, each
// wave covers 128 output cols (2 heads). q gets scale*log2e folded in.
// f32 inputs converted to bf16 inline (no prep kernel).
__global__ __launch_bounds__(256) void k_qkv(const float* __restrict__ xin,
    const float* __restrict__ Wq, const float* __restrict__ Wk,
    const float* __restrict__ Wv, const float* __restrict__ scale,
    ushort* __restrict__ q_bf, ushort* __restrict__ k_bf, ushort* __restrict__ vT){
  const int z = blockIdx.y;
  const int n0 = blockIdx.x * 16;
  const int lane = threadIdx.x & 63, w = threadIdx.x >> 6;
  const int l15 = lane & 15, g = lane >> 4;
  const int obase = w * 128;
  const float* W = (z==0) ? Wq : (z==1) ? Wk : Wv;
  // A: x[n0+l15][c-chunks] gathered from xin [64][4096]
  const int n = n0 + l15;
  float xa[8], xc[8];
#pragma unroll
  for (int j=0;j<8;j++){
    xa[j] = xin[(8*g + j)*4096 + n];
    xc[j] = xin[(32 + 8*g + j)*4096 + n];
  }
  union{ i32x4 i; bf16x8 v; } ua, uc;
  ua.i[0]=cvtpk(xa[0],xa[1]); ua.i[1]=cvtpk(xa[2],xa[3]);
  ua.i[2]=cvtpk(xa[4],xa[5]); ua.i[3]=cvtpk(xa[6],xa[7]);
  uc.i[0]=cvtpk(xc[0],xc[1]); uc.i[1]=cvtpk(xc[2],xc[3]);
  uc.i[2]=cvtpk(xc[4],xc[5]); uc.i[3]=cvtpk(xc[6],xc[7]);
  bf16x8 a0 = ua.v, a1 = uc.v;
  f32x4 acc[8];
#pragma unroll
  for (int t=0;t<8;t++) acc[t] = (f32x4){0.f,0.f,0.f,0.f};
#pragma unroll
  for (int t=0;t<8;t++){
    const float* brow = W + (size_t)(obase + 16*t + l15)*64;
    bf16x8 b0 = packf8(brow + 8*g);
    bf16x8 b1 = packf8(brow + 32 + 8*g);
    acc[t] = __builtin_amdgcn_mfma_f32_16x16x32_bf16(a0, b0, acc[t], 0,0,0);
    acc[t] = __builtin_amdgcn_mfma_f32_16x16x32_bf16(a1, b1, acc[t], 0,0,0);
  }
  if (z < 2){  // cosine normalization per (row, head); head = 64 consecutive cols
#pragma unroll
    for (int hh=0; hh<2; hh++){
      float sfac = (z==0) ? (scale[2*w+hh] * LOG2E) : 1.0f;
#pragma unroll
      for (int r=0;r<4;r++){
        float ss = 0.f;
#pragma unroll
        for (int tt=0;tt<4;tt++){ float v = acc[hh*4+tt][r]; ss += v*v; }
        ss += __shfl_xor(ss, 1); ss += __shfl_xor(ss, 2);
        ss += __shfl_xor(ss, 4); ss += __shfl_xor(ss, 8);
        float inv = sfac / fmaxf(sqrtf(ss), 1e-12f);
#pragma unroll
        for (int tt=0;tt<4;tt++) acc[hh*4+tt][r] *= inv;
      }
    }
    ushort* dst = (z==0) ? q_bf : k_bf;
#pragma unroll
    for (int t=0;t<8;t++){
      int col = obase + 16*t + l15;
#pragma unroll
      for (int r=0;r<4;r++)
        dst[(size_t)(n0 + 4*g + r)*512 + col] = f2bf(acc[t][r]);
    }
  } else {
    // v: store transposed bf16 [d][n] (serves attention V-frags AND conv branch)
#pragma unroll
    for (int t=0;t<8;t++){
      int col = obase + 16*t + l15;
      u16x4 vs;
#pragma unroll
      for (int r=0;r<4;r++) vs[r] = f2bf(acc[t][r]);
      *(u16x4*)(vT + (size_t)col*4096 + n0 + 4*g) = vs;
    }
  }
}

// ---------------- K3: flash attention, LDS-free, 64q/wave, kv-split --------
// 1-wave blocks. block = (qb 64 rows, head, kv-segment). K/V fragments loaded
// directly from global (64B-line coalesced, L2-resident). No barriers.
// Scores bounded (cosine-norm) -> no-max softmax -> partials are pure sums.
__global__ __launch_bounds__(64) void k_attn(const ushort* __restrict__ q_bf,
    const ushort* __restrict__ k_bf, const ushort* __restrict__ vT,
    float* __restrict__ O_part, float* __restrict__ lsum_part, int log2S){
  const int S = 1 << log2S;
  const int lin = blockIdx.x;
  const int c = lin & (8*S - 1);          // (h,seg) combo -> XCD-local
  const int qb = lin >> (3 + log2S);
  const int h = c >> log2S;
  const int seg = c & (S - 1);
  const int segLen = 4096 >> log2S;
  const int kv0 = seg * segLen;
  const int lane = threadIdx.x;
  const int l15 = lane & 15, g = lane >> 4;

  bf16x8 qa[4][2];
#pragma unroll
  for (int tq=0;tq<4;tq++){
    const ushort* qrow = q_bf + (size_t)(qb*64 + tq*16 + l15)*512 + h*64;
    qa[tq][0] = *(const bf16x8*)(qrow + 8*g);
    qa[tq][1] = *(const bf16x8*)(qrow + 32 + 8*g);
  }
  f32x4 O[4][4];
#pragma unroll
  for (int tq=0;tq<4;tq++)
#pragma unroll
    for (int t=0;t<4;t++) O[tq][t] = (f32x4){0.f,0.f,0.f,0.f};
  float lsum[4] = {0.f,0.f,0.f,0.f};

  const ushort* Kbase = k_bf + (size_t)kv0*512 + h*64;
  const ushort* Vbase = vT + (size_t)(h*64)*4096 + kv0;
  const int iters = segLen >> 6;

  for (int it = 0; it < iters; ++it){
    const ushort* Kp = Kbase + (size_t)it*64*512;
    const ushort* Vp = Vbase + it*64;
    bf16x8 kf[4][2];
#pragma unroll
    for (int s=0;s<4;s++){
      const ushort* kr = Kp + (size_t)(16*s + l15)*512;
      kf[s][0] = *(const bf16x8*)(kr + 8*g);
      kf[s][1] = *(const bf16x8*)(kr + 32 + 8*g);
    }
    bf16x8 vf[4][2];
#pragma unroll
    for (int t=0;t<4;t++){
      const ushort* vr = Vp + (size_t)(16*t + l15)*4096;
      union { bf16x8 v; i32x2 h2[2]; } u0, u1;
      u0.h2[0] = *(const i32x2*)(vr + 4*g);
      u0.h2[1] = *(const i32x2*)(vr + 16 + 4*g);
      u1.h2[0] = *(const i32x2*)(vr + 32 + 4*g);
      u1.h2[1] = *(const i32x2*)(vr + 48 + 4*g);
      vf[t][0] = u0.v; vf[t][1] = u1.v;
    }
    // QK^T (S^T: row=key, col=q) -> exp2 -> pack PV A-frags in-register
    i32x4 PA[4][2];
#pragma unroll
    for (int s=0;s<4;s++){
      const int sp = s >> 1, hi = (s & 1) << 1;  // words hi,hi+1 of PA[.][sp]
#pragma unroll
      for (int tq=0;tq<4;tq++){
        f32x4 st = (f32x4){0.f,0.f,0.f,0.f};
        st = __builtin_amdgcn_mfma_f32_16x16x32_bf16(kf[s][0], qa[tq][0], st, 0,0,0);
        st = __builtin_amdgcn_mfma_f32_16x16x32_bf16(kf[s][1], qa[tq][1], st, 0,0,0);
        float p0 = exp2_(st[0]), p1 = exp2_(st[1]);
        float p2 = exp2_(st[2]), p3 = exp2_(st[3]);
        lsum[tq] += (p0 + p1) + (p2 + p3);
        PA[tq][sp][hi]   = cvtpk(p0, p1);
        PA[tq][sp][hi+1] = cvtpk(p2, p3);
      }
    }
    // PV: O[tq][t] += P(tq) x V(t)
#pragma unroll
    for (int t=0;t<4;t++){
#pragma unroll
      for (int tq=0;tq<4;tq++){
        union { i32x4 i; bf16x8 v; } a0, a1;
        a0.i = PA[tq][0]; a1.i = PA[tq][1];
        O[tq][t] = __builtin_amdgcn_mfma_f32_16x16x32_bf16(a0.v, vf[t][0], O[tq][t], 0,0,0);
        O[tq][t] = __builtin_amdgcn_mfma_f32_16x16x32_bf16(a1.v, vf[t][1], O[tq][t], 0,0,0);
      }
    }
  }
  // per-q softmax partial denominators
#pragma unroll
  for (int tq=0;tq<4;tq++){
    float ls = lsum[tq];
    ls += __shfl_xor(ls, 16); ls += __shfl_xor(ls, 32);
    if (g == 0)
      lsum_part[((size_t)seg*8 + h)*4096 + qb*64 + tq*16 + l15] = ls;
  }
  float* Op = O_part + (size_t)seg*4096*512;
#pragma unroll
  for (int tq=0;tq<4;tq++)
#pragma unroll
    for (int t=0;t<4;t++)
#pragma unroll
      for (int r=0;r<4;r++)
        Op[(size_t)(qb*64 + tq*16 + 4*g + r)*512 + h*64 + 16*t + l15] = O[tq][t][r];
}

// ---------------- K3b: combine kv-split partials -> att_bf + pooled --------
__global__ __launch_bounds__(256) void k_comb(const float* __restrict__ O_part,
    const float* __restrict__ lsum_part, ushort* __restrict__ att_bf,
    float* __restrict__ pooled, int S){
  __shared__ float Linv[16][8];
  const int qbase = blockIdx.x * 16;
  const int tid = threadIdx.x;
  if (tid < 128){
    int q = tid >> 3, h = tid & 7;
    float L = 0.f;
    for (int s=0;s<S;s++) L += lsum_part[((size_t)s*8 + h)*4096 + qbase + q];
    Linv[q][h] = 1.0f / L;
  }
  __syncthreads();
  const int d2 = tid*2;
  const int h = d2 >> 6;
  float pool0 = 0.f, pool1 = 0.f;
  for (int q=0;q<16;q++){
    size_t idx = (size_t)(qbase + q)*512 + d2;
    float o0 = 0.f, o1 = 0.f;
    for (int s=0;s<S;s++){
      f32x2 ov = *(const f32x2*)(O_part + (size_t)s*4096*512 + idx);
      o0 += ov[0]; o1 += ov[1];
    }
    float li = Linv[q][h];
    o0 *= li; o1 *= li;
    uint pk = (uint)f2bf(o0) | ((uint)f2bf(o1) << 16);
    *(uint*)(att_bf + idx) = pk;
    pool0 += o0; pool1 += o1;
  }
  atomicAdd(&pooled[d2], pool0);
  atomicAdd(&pooled[d2+1], pool1);
}

// ---------------- K4: depthwise 3x3 + bias + BN + GELU (bf16 in/out) -------
__global__ __launch_bounds__(256) void k_conv(const ushort* __restrict__ vT,
    const float* __restrict__ dw_w, const float* __restrict__ dw_b,
    const float* __restrict__ dw_g, const float* __restrict__ dw_bt,
    const float* __restrict__ dw_m, const float* __restrict__ dw_v,
    ushort* __restrict__ conv_x){
  __shared__ float tile[4096];
  const int d = blockIdx.x;
  const int tid = threadIdx.x;
  const ushort* src = vT + (size_t)d*4096;
  {
    bf16x8 a = *(const bf16x8*)(src + tid*16);
    bf16x8 b = *(const bf16x8*)(src + tid*16 + 8);
#pragma unroll
    for (int j=0;j<8;j++){
      tile[tid*16 + j]     = bf2f((ushort)a[j]);
      tile[tid*16 + 8 + j] = bf2f((ushort)b[j]);
    }
  }
  __syncthreads();
  float wv[9];
#pragma unroll
  for (int i=0;i<9;i++) wv[i] = dw_w[d*9+i];
  const float bias = dw_b[d];
  const float bnsc = dw_g[d] * rsqrtf(dw_v[d] + 1e-5f);
  const float bnb  = dw_bt[d] - dw_m[d]*bnsc;
  ushort* dst = conv_x + (size_t)d*4096;
#pragma unroll 4
  for (int i=0;i<16;i++){
    int p = tid + 256*i;
    int y = p >> 6, x = p & 63;
    float acc = 0.f;
#pragma unroll
    for (int ky=0;ky<3;ky++){
      int yy = y + ky - 1;
      if (yy < 0 || yy > 63) continue;
#pragma unroll
      for (int kx=0;kx<3;kx++){
        int xx = x + kx - 1;
        if (xx < 0 || xx > 63) continue;
        acc += wv[ky*3+kx] * tile[yy*64 + xx];
      }
    }
    float cc = (acc + bias)*bnsc + bnb;
    dst[p] = f2bf(gelu_(cc));
  }
}

// ---------------- K5+K6: spatial (blocks 0..255) + channel (block 256) -----
__global__ __launch_bounds__(256) void k_sc(const ushort* __restrict__ conv_x,
    const float* __restrict__ si_w1, const float* __restrict__ si_b1,
    const float* __restrict__ si_g, const float* __restrict__ si_bt,
    const float* __restrict__ si_m, const float* __restrict__ si_v,
    const float* __restrict__ si_w2, const float* __restrict__ si_b2,
    float* __restrict__ sig_sm,
    const float* __restrict__ pooled, const float* __restrict__ ci_w1,
    const float* __restrict__ ci_b1, const float* __restrict__ ci_w2,
    const float* __restrict__ ci_b2, float* __restrict__ sig_cm){
  const int tid = threadIdx.x;
  if (blockIdx.x == 256){
    // channel interaction MLP on pooled mean
    __shared__ float pl[512];
    __shared__ float h1[128];
    pl[tid]       = pooled[tid]       * (1.0f/4096.0f);
    pl[tid + 256] = pooled[tid + 256] * (1.0f/4096.0f);
    __syncthreads();
    if (tid < 128){
      float acc = ci_b1[tid];
      const float* wr = ci_w1 + (size_t)tid*512;
#pragma unroll 4
      for (int c=0;c<512;c++) acc += wr[c]*pl[c];
      h1[tid] = gelu_(acc);
    }
    __syncthreads();
#pragma unroll
    for (int dd=0; dd<2; dd++){
      int d = tid + 256*dd;
      float acc = ci_b2[d];
      const float* wr = ci_w2 + (size_t)d*128;
#pragma unroll 4
      for (int e=0;e<128;e++) acc += wr[e]*h1[e];
      sig_cm[d] = sigmoid_(acc);
    }
    return;
  }
  __shared__ float red[16];
  const int n0 = blockIdx.x * 16;
  const int nl = tid & 15;
  const int eg = tid >> 4;
  const int n = n0 + nl;
  float a0 = 0.f, a1 = 0.f;
  const float* w1a = si_w1 + (size_t)(2*eg)*512;
  const float* w1b = w1a + 512;
#pragma unroll 4
  for (int d=0; d<512; d++){
    float x = bf2f(conv_x[(size_t)d*4096 + n]);
    a0 += w1a[d]*x;
    a1 += w1b[d]*x;
  }
  float outp = 0.f;
  {
    int e = 2*eg;
    float s = si_g[e] * rsqrtf(si_v[e] + 1e-5f);
    float v = (a0 + si_b1[e] - si_m[e]) * s + si_bt[e];
    outp += si_w2[e] * gelu_(v);
    e = 2*eg + 1;
    s = si_g[e] * rsqrtf(si_v[e] + 1e-5f);
    v = (a1 + si_b1[e] - si_m[e]) * s + si_bt[e];
    outp += si_w2[e] * gelu_(v);
  }
  if (tid < 16) red[tid] = 0.f;
  __syncthreads();
  atomicAdd(&red[nl], outp);
  __syncthreads();
  if (tid < 16) sig_sm[n0 + tid] = sigmoid_(red[tid] + si_b2[0]);
}

// ---------------- K8: positional-embed branch: dw3x3 -> gelu -> dw3x3 ------
__global__ __launch_bounds__(256) void k_pe(const float* __restrict__ xin,
    const float* __restrict__ pe_w1, const float* __restrict__ pe_w2,
    float* __restrict__ embed){
  __shared__ float t0[4096];
  __shared__ float t1[4096];
  const int c = blockIdx.x;
  const int tid = threadIdx.x;
  const float* src = xin + (size_t)c*4096;
#pragma unroll
  for (int i=0;i<16;i++) t0[tid + 256*i] = src[tid + 256*i];
  __syncthreads();
  float w1[9], w2[9];
#pragma unroll
  for (int i=0;i<9;i++){ w1[i] = pe_w1[c*9+i]; w2[i] = pe_w2[c*9+i]; }
#pragma unroll 4
  for (int i=0;i<16;i++){
    int p = tid + 256*i;
    int y = p >> 6, x = p & 63;
    float acc = 0.f;
#pragma unroll
    for (int ky=0;ky<3;ky++){
      int yy = y + ky - 1;
      if (yy < 0 || yy > 63) continue;
#pragma unroll
      for (int kx=0;kx<3;kx++){
        int xx = x + kx - 1;
        if (xx < 0 || xx > 63) continue;
        acc += w1[ky*3+kx] * t0[yy*64 + xx];
      }
    }
    t1[p] = gelu_(acc);
  }
  __syncthreads();
  float* dst = embed + (size_t)c*4096;
#pragma unroll 4
  for (int i=0;i<16;i++){
    int p = tid + 256*i;
    int y = p >> 6, x = p & 63;
    float acc = 0.f;
#pragma unroll
    for (int ky=0;ky<3;ky++){
      int yy = y + ky - 1;
      if (yy < 0 || yy > 63) continue;
#pragma unroll
      for (int kx=0;kx<3;kx++){
        int xx = x + kx - 1;
        if (xx < 0 || xx > 63) continue;
        acc += w2[ky*3+kx] * t1[yy*64 + xx];
      }
    }
    dst[p] = acc;
  }
}

// ---------------- K7: gate fuse + output GEMM + embed add -----------------
// grid 256, block 64 (1 wave): 16 rows x 64 out-cols per wave. Wout f32 -> bf16 inline.
__global__ __launch_bounds__(64) void k_final(const ushort* __restrict__ att_bf,
    const ushort* __restrict__ conv_x, const float* __restrict__ sig_sm,
    const float* __restrict__ sig_cm, const float* __restrict__ Wout,
    const float* __restrict__ bout, const float* __restrict__ embed,
    float* __restrict__ out){
  const int lane = threadIdx.x;
  const int l15 = lane & 15, g = lane >> 4;
  const int n0 = blockIdx.x * 16;
  const int rowA = n0 + l15;
  const float srow = sig_sm[rowA];
  f32x4 acc[4];
#pragma unroll
  for (int t=0;t<4;t++) acc[t] = (f32x4){0.f,0.f,0.f,0.f};
#pragma unroll 2
  for (int kk=0;kk<16;kk++){
    int k0 = kk*32;
    bf16x8 at8 = *(const bf16x8*)(att_bf + (size_t)rowA*512 + k0 + 8*g);
    bf16x8 af;
#pragma unroll
    for (int i=0;i<8;i++){
      int d = k0 + 8*g + i;
      float zv = bf2f((ushort)at8[i]) * srow
               + bf2f(conv_x[(size_t)d*4096 + rowA]) * sig_cm[d];
      af[i] = (short)f2bf(zv);
    }
#pragma unroll
    for (int t=0;t<4;t++){
      bf16x8 bf8 = packf8(Wout + (size_t)(16*t+l15)*512 + k0 + 8*g);
      acc[t] = __builtin_amdgcn_mfma_f32_16x16x32_bf16(af, bf8, acc[t], 0,0,0);
    }
  }
#pragma unroll
  for (int t=0;t<4;t++){
    int o = 16*t + l15;
    float bo = bout[o];
#pragma unroll
    for (int r=0;r<4;r++){
      int row = n0 + 4*g + r;
      size_t idx = (size_t)row*64 + o;
      out[idx] = acc[t][r] + bo + embed[idx];
    }
  }
}

extern "C" void kernel_launch(void* const* d_in, const int* in_sizes, int n_in,
                              void* d_out, int out_size, void* d_ws, size_t ws_size,
                              hipStream_t stream){
  (void)in_sizes; (void)n_in; (void)out_size;
  const float* x_in  = (const float*)d_in[0];
  const float* Wq    = (const float*)d_in[1];
  const float* Wk    = (const float*)d_in[2];
  const float* Wv    = (const float*)d_in[3];
  const float* scale = (const float*)d_in[4];
  const float* Wout  = (const float*)d_in[5];
  const float* bout  = (const float*)d_in[6];
  const float* dw_w  = (const float*)d_in[7];
  const float* dw_b  = (const float*)d_in[8];
  const float* dw_g  = (const float*)d_in[9];
  const float* dw_bt = (const float*)d_in[10];
  const float* dw_m  = (const float*)d_in[11];
  const float* dw_v  = (const float*)d_in[12];
  const float* ci_w1 = (const float*)d_in[13];
  const float* ci_b1 = (const float*)d_in[14];
  const float* ci_w2 = (const float*)d_in[15];
  const float* ci_b2 = (const float*)d_in[16];
  const float* si_w1 = (const float*)d_in[17];
  const float* si_b1 = (const float*)d_in[18];
  const float* si_g  = (const float*)d_in[19];
  const float* si_bt = (const float*)d_in[20];
  const float* si_m  = (const float*)d_in[21];
  const float* si_v  = (const float*)d_in[22];
  const float* si_w2 = (const float*)d_in[23];
  const float* si_b2 = (const float*)d_in[24];
  const float* pe_w1 = (const float*)d_in[25];
  const float* pe_w2 = (const float*)d_in[26];
  float* out = (float*)d_out;

  char* p = (char*)d_ws;
  auto alloc = [&](size_t bytes)->char*{
    char* r = p; p += (bytes + 255) & ~(size_t)255; return r;
  };
  ushort* q_bf   = (ushort*)alloc((size_t)4096*512*2);
  ushort* k_bf   = (ushort*)alloc((size_t)4096*512*2);
  ushort* vTb    = (ushort*)alloc((size_t)512*4096*2);
  ushort* att_bf = (ushort*)alloc((size_t)4096*512*2);
  ushort* conv_x = (ushort*)alloc((size_t)512*4096*2);
  float*  embed  = (float*) alloc((size_t)64*4096*4);
  float*  lsum_p = (float*) alloc((size_t)4*8*4096*4);
  float*  pooled = (float*) alloc(512*4);
  float*  sig_sm = (float*) alloc(4096*4);
  float*  sig_cm = (float*) alloc(512*4);
  size_t used = (size_t)(p - (char*)d_ws);
  size_t segBytes = (size_t)4096*512*4 + 256;
  size_t avail = (ws_size > used) ? (ws_size - used) : 0;
  int log2S = 2;
  if (avail < 4*segBytes) log2S = 1;
  if (avail < 2*segBytes) log2S = 0;
  int S = 1 << log2S;
  float* O_part = (float*)alloc((size_t)S*segBytes);

  k_qkv<<<dim3(256,3), 256, 0, stream>>>(x_in, Wq, Wk, Wv, scale, q_bf, k_bf, vTb);
  k_attn<<<64*8*S, 64, 0, stream>>>(q_bf, k_bf, vTb, O_part, lsum_p, log2S);
  hipMemsetAsync(pooled, 0, 512*4, stream);
  k_comb<<<256, 256, 0, stream>>>(O_part, lsum_p, att_bf, pooled, S);
  k_conv<<<512, 256, 0, stream>>>(vTb, dw_w, dw_b, dw_g, dw_bt, dw_m, dw_v, conv_x);
  k_sc<<<257, 256, 0, stream>>>(conv_x, si_w1, si_b1, si_g, si_bt, si_m, si_v,
                                si_w2, si_b2, sig_sm,
                                pooled, ci_w1, ci_b1, ci_w2, ci_b2, sig_cm);
  k_pe<<<64, 256, 0, stream>>>(x_in, pe_w1, pe_w2, embed);
  k_final<<<256, 64, 0, stream>>>(att_bf, conv_x, sig_sm, sig_cm, Wout, bout, embed, out);
}

// Round 4
// 173.028 us; speedup vs baseline: 1.3993x; 1.3993x over previous
//
#include <hip/hip_runtime.h>

// MultiAttention fused pipeline for MI355X (gfx950).
// B=1, C=64, H=W=64 (N=4096), NH=8, DK=64, D=512.

#define LOG2E 1.442695040888963f

typedef __attribute__((ext_vector_type(8))) short bf16x8;
typedef __attribute__((ext_vector_type(4))) float f32x4;
typedef __attribute__((ext_vector_type(2))) float f32x2;
typedef __attribute__((ext_vector_type(4))) int i32x4;
typedef __attribute__((ext_vector_type(2))) int i32x2;
typedef __attribute__((ext_vector_type(4))) ushort u16x4;

__device__ __forceinline__ ushort f2bf(float x){
  uint u = __float_as_uint(x);
  u += 0x7fffu + ((u >> 16) & 1u);   // round-to-nearest-even
  return (ushort)(u >> 16);
}
__device__ __forceinline__ float bf2f(ushort h){
  return __uint_as_float(((uint)h) << 16);
}
__device__ __forceinline__ float gelu_(float x){
  return 0.5f * x * (1.0f + erff(x * 0.70710678118654752f));
}
__device__ __forceinline__ float sigmoid_(float x){
  return 1.0f / (1.0f + __expf(-x));
}
__device__ __forceinline__ float exp2_(float x){
  float r; asm("v_exp_f32 %0, %1" : "=v"(r) : "v"(x)); return r;
}
__device__ __forceinline__ int cvtpk(float lo, float hi){
  int r; asm("v_cvt_pk_bf16_f32 %0, %1, %2" : "=v"(r) : "v"(lo), "v"(hi)); return r;
}
__device__ __forceinline__ bf16x8 packf8(const float* s){
  f32x4 x0 = *(const f32x4*)s;
  f32x4 x1 = *(const f32x4*)(s+4);
  union{ i32x4 i; bf16x8 v; } u;
  u.i[0]=cvtpk(x0[0],x0[1]); u.i[1]=cvtpk(x0[2],x0[3]);
  u.i[2]=cvtpk(x1[0],x1[1]); u.i[3]=cvtpk(x1[2],x1[3]);
  return u.v;
}

// ---------------- K2: QKV projection (MFMA) + cosine norm for q,k ----------
// grid (256, 3): 16 rows/block, z = 0:q 1:k 2:v. q gets scale*log2e folded in.
__global__ __launch_bounds__(256) void k_qkv(const float* __restrict__ xin,
    const float* __restrict__ Wq, const float* __restrict__ Wk,
    const float* __restrict__ Wv, const float* __restrict__ scale,
    ushort* __restrict__ q_bf, ushort* __restrict__ k_bf, ushort* __restrict__ vT){
  const int z = blockIdx.y;
  const int n0 = blockIdx.x * 16;
  const int lane = threadIdx.x & 63, w = threadIdx.x >> 6;
  const int l15 = lane & 15, g = lane >> 4;
  const int obase = w * 128;
  const float* W = (z==0) ? Wq : (z==1) ? Wk : Wv;
  const int n = n0 + l15;
  float xa[8], xc[8];
#pragma unroll
  for (int j=0;j<8;j++){
    xa[j] = xin[(8*g + j)*4096 + n];
    xc[j] = xin[(32 + 8*g + j)*4096 + n];
  }
  union{ i32x4 i; bf16x8 v; } ua, uc;
  ua.i[0]=cvtpk(xa[0],xa[1]); ua.i[1]=cvtpk(xa[2],xa[3]);
  ua.i[2]=cvtpk(xa[4],xa[5]); ua.i[3]=cvtpk(xa[6],xa[7]);
  uc.i[0]=cvtpk(xc[0],xc[1]); uc.i[1]=cvtpk(xc[2],xc[3]);
  uc.i[2]=cvtpk(xc[4],xc[5]); uc.i[3]=cvtpk(xc[6],xc[7]);
  bf16x8 a0 = ua.v, a1 = uc.v;
  f32x4 acc[8];
#pragma unroll
  for (int t=0;t<8;t++) acc[t] = (f32x4){0.f,0.f,0.f,0.f};
#pragma unroll
  for (int t=0;t<8;t++){
    const float* brow = W + (size_t)(obase + 16*t + l15)*64;
    bf16x8 b0 = packf8(brow + 8*g);
    bf16x8 b1 = packf8(brow + 32 + 8*g);
    acc[t] = __builtin_amdgcn_mfma_f32_16x16x32_bf16(a0, b0, acc[t], 0,0,0);
    acc[t] = __builtin_amdgcn_mfma_f32_16x16x32_bf16(a1, b1, acc[t], 0,0,0);
  }
  if (z < 2){
#pragma unroll
    for (int hh=0; hh<2; hh++){
      float sfac = (z==0) ? (scale[2*w+hh] * LOG2E) : 1.0f;
#pragma unroll
      for (int r=0;r<4;r++){
        float ss = 0.f;
#pragma unroll
        for (int tt=0;tt<4;tt++){ float v = acc[hh*4+tt][r]; ss += v*v; }
        ss += __shfl_xor(ss, 1); ss += __shfl_xor(ss, 2);
        ss += __shfl_xor(ss, 4); ss += __shfl_xor(ss, 8);
        float inv = sfac / fmaxf(sqrtf(ss), 1e-12f);
#pragma unroll
        for (int tt=0;tt<4;tt++) acc[hh*4+tt][r] *= inv;
      }
    }
    ushort* dst = (z==0) ? q_bf : k_bf;
#pragma unroll
    for (int t=0;t<8;t++){
      int col = obase + 16*t + l15;
#pragma unroll
      for (int r=0;r<4;r++)
        dst[(size_t)(n0 + 4*g + r)*512 + col] = f2bf(acc[t][r]);
    }
  } else {
#pragma unroll
    for (int t=0;t<8;t++){
      int col = obase + 16*t + l15;
      u16x4 vs;
#pragma unroll
      for (int r=0;r<4;r++) vs[r] = f2bf(acc[t][r]);
      *(u16x4*)(vT + (size_t)col*4096 + n0 + 4*g) = vs;
    }
  }
}

// ---------------- K3: flash attention, LDS-staged, 64q/wave, kv-split ------
// block = 256 thr (4 waves), each wave 64 q-rows -> block covers 256 q.
// grid = 16 qb * 8 h * S. (h,seg) combo in low bits -> pinned per XCD.
// K,V tiles double-buffered in LDS with XOR bank swizzle; 1 barrier/iter.
// Scores cosine-normalized -> no-max softmax -> kv-split partials pure sums.
__global__ __launch_bounds__(256) void k_attn(const ushort* __restrict__ q_bf,
    const ushort* __restrict__ k_bf, const ushort* __restrict__ vT,
    float* __restrict__ O_part, float* __restrict__ lsum_part, int log2S){
  __shared__ ushort Kt[2][4096];
  __shared__ ushort Vt[2][4096];
  const int S = 1 << log2S;
  const int lin = blockIdx.x;
  const int combo = lin & (8*S - 1);
  const int qb = lin >> (3 + log2S);
  const int h = combo >> log2S;
  const int seg = combo & (S - 1);
  const int kv0 = seg * (4096 >> log2S);
  const int iters = (4096 >> log2S) >> 6;
  const int tid = threadIdx.x;
  const int lane = tid & 63, w = tid >> 6;
  const int l15 = lane & 15, g = lane >> 4;

  // staging: thread -> (row = 16*wave + l, 16-col chunk cb); 32B each of K,V
  const int sl = tid & 15, scb = (tid >> 4) & 3;
  const int srow = (tid >> 6)*16 + sl;
  const ushort* gK = k_bf + (size_t)(kv0 + srow)*512 + h*64 + scb*16;
  const ushort* gV = vT + (size_t)(h*64 + srow)*4096 + kv0 + scb*16;
  const int wO0 = srow*64 + (((2*scb)   ^ (srow & 7)) << 3);
  const int wO1 = srow*64 + (((2*scb+1) ^ (srow & 7)) << 3);

  // Q fragments: 64 rows per wave (4 tiles of 16)
  const int qrow0 = qb*256 + w*64;
  bf16x8 qa[4][2];
#pragma unroll
  for (int tq=0;tq<4;tq++){
    const ushort* qrow = q_bf + (size_t)(qrow0 + tq*16 + l15)*512 + h*64;
    qa[tq][0] = *(const bf16x8*)(qrow + 8*g);
    qa[tq][1] = *(const bf16x8*)(qrow + 32 + 8*g);
  }
  f32x4 O[4][4];
#pragma unroll
  for (int tq=0;tq<4;tq++)
#pragma unroll
    for (int t=0;t<4;t++) O[tq][t] = (f32x4){0.f,0.f,0.f,0.f};
  float lsum[4] = {0.f,0.f,0.f,0.f};

  // stage tile 0
  {
    i32x4 a = *(const i32x4*)gK, b = *(const i32x4*)(gK+8);
    i32x4 c = *(const i32x4*)gV, d = *(const i32x4*)(gV+8);
    *(i32x4*)&Kt[0][wO0] = a; *(i32x4*)&Kt[0][wO1] = b;
    *(i32x4*)&Vt[0][wO0] = c; *(i32x4*)&Vt[0][wO1] = d;
  }
  int buf = 0;
  const int x7 = l15 & 7;
  const int g2 = g >> 1, gh = (g & 1) << 2;

  for (int it = 0; it < iters; ++it){
    __syncthreads();
    i32x4 nk0, nk1, nv0, nv1;
    const bool pf = (it + 1 < iters);
    if (pf){
      gK += 64*512; gV += 64;
      nk0 = *(const i32x4*)gK; nk1 = *(const i32x4*)(gK+8);
      nv0 = *(const i32x4*)gV; nv1 = *(const i32x4*)(gV+8);
    }
    const ushort* Kb = Kt[buf];
    const ushort* Vb = Vt[buf];
    // QK^T (S^T: row=key, col=q) -> exp2 -> pack PV A-frags in-register
    i32x4 PA[4][2];
#pragma unroll
    for (int s=0;s<4;s++){
      const int rr = 16*s + l15;
      bf16x8 kf0 = *(const bf16x8*)&Kb[rr*64 + ((g     ^ x7) << 3)];
      bf16x8 kf1 = *(const bf16x8*)&Kb[rr*64 + (((4+g) ^ x7) << 3)];
      const int sp = s >> 1, hi = (s & 1) << 1;
#pragma unroll
      for (int tq=0;tq<4;tq++){
        f32x4 st = (f32x4){0.f,0.f,0.f,0.f};
        st = __builtin_amdgcn_mfma_f32_16x16x32_bf16(kf0, qa[tq][0], st, 0,0,0);
        st = __builtin_amdgcn_mfma_f32_16x16x32_bf16(kf1, qa[tq][1], st, 0,0,0);
        float p0 = exp2_(st[0]), p1 = exp2_(st[1]);
        float p2 = exp2_(st[2]), p3 = exp2_(st[3]);
        lsum[tq] += (p0 + p1) + (p2 + p3);
        PA[tq][sp][hi]   = cvtpk(p0, p1);
        PA[tq][sp][hi+1] = cvtpk(p2, p3);
      }
    }
    // PV
#pragma unroll
    for (int t=0;t<4;t++){
      const int rr = 16*t + l15;
      union { bf16x8 v; i32x2 h2[2]; } u0, u1;
      u0.h2[0] = *(const i32x2*)&Vb[rr*64 + ((g2       ^ x7) << 3) + gh];
      u0.h2[1] = *(const i32x2*)&Vb[rr*64 + (((2 + g2) ^ x7) << 3) + gh];
      u1.h2[0] = *(const i32x2*)&Vb[rr*64 + (((4 + g2) ^ x7) << 3) + gh];
      u1.h2[1] = *(const i32x2*)&Vb[rr*64 + (((6 + g2) ^ x7) << 3) + gh];
#pragma unroll
      for (int tq=0;tq<4;tq++){
        union { i32x4 i; bf16x8 v; } a0, a1;
        a0.i = PA[tq][0]; a1.i = PA[tq][1];
        O[tq][t] = __builtin_amdgcn_mfma_f32_16x16x32_bf16(a0.v, u0.v, O[tq][t], 0,0,0);
        O[tq][t] = __builtin_amdgcn_mfma_f32_16x16x32_bf16(a1.v, u1.v, O[tq][t], 0,0,0);
      }
    }
    if (pf){
      ushort* Kn = Kt[buf^1];
      ushort* Vn = Vt[buf^1];
      *(i32x4*)&Kn[wO0] = nk0; *(i32x4*)&Kn[wO1] = nk1;
      *(i32x4*)&Vn[wO0] = nv0; *(i32x4*)&Vn[wO1] = nv1;
    }
    buf ^= 1;
  }
  // partial softmax denominators (sum over g-groups; q = l15 col labeling)
#pragma unroll
  for (int tq=0;tq<4;tq++){
    float ls = lsum[tq];
    ls += __shfl_xor(ls, 16); ls += __shfl_xor(ls, 32);
    if (g == 0)
      lsum_part[((size_t)seg*8 + h)*4096 + qrow0 + tq*16 + l15] = ls;
  }
  float* Op = O_part + (size_t)seg*4096*512;
#pragma unroll
  for (int tq=0;tq<4;tq++)
#pragma unroll
    for (int t=0;t<4;t++)
#pragma unroll
      for (int r=0;r<4;r++)
        Op[(size_t)(qrow0 + tq*16 + 4*g + r)*512 + h*64 + 16*t + l15] = O[tq][t][r];
}

// ---------------- K3b: combine kv-split partials -> att_bf + pooled --------
__global__ __launch_bounds__(256) void k_comb(const float* __restrict__ O_part,
    const float* __restrict__ lsum_part, ushort* __restrict__ att_bf,
    float* __restrict__ pooled, int S){
  __shared__ float Linv[16][8];
  const int qbase = blockIdx.x * 16;
  const int tid = threadIdx.x;
  if (tid < 128){
    int q = tid >> 3, h = tid & 7;
    float L = 0.f;
    for (int s=0;s<S;s++) L += lsum_part[((size_t)s*8 + h)*4096 + qbase + q];
    Linv[q][h] = 1.0f / L;
  }
  __syncthreads();
  const int d2 = tid*2;
  const int h = d2 >> 6;
  float pool0 = 0.f, pool1 = 0.f;
  for (int q=0;q<16;q++){
    size_t idx = (size_t)(qbase + q)*512 + d2;
    float o0 = 0.f, o1 = 0.f;
    for (int s=0;s<S;s++){
      f32x2 ov = *(const f32x2*)(O_part + (size_t)s*4096*512 + idx);
      o0 += ov[0]; o1 += ov[1];
    }
    float li = Linv[q][h];
    o0 *= li; o1 *= li;
    uint pk = (uint)f2bf(o0) | ((uint)f2bf(o1) << 16);
    *(uint*)(att_bf + idx) = pk;
    pool0 += o0; pool1 += o1;
  }
  atomicAdd(&pooled[d2], pool0);
  atomicAdd(&pooled[d2+1], pool1);
}

// ---------------- K4: depthwise 3x3 + bias + BN + GELU (bf16 in/out) -------
__global__ __launch_bounds__(256) void k_conv(const ushort* __restrict__ vT,
    const float* __restrict__ dw_w, const float* __restrict__ dw_b,
    const float* __restrict__ dw_g, const float* __restrict__ dw_bt,
    const float* __restrict__ dw_m, const float* __restrict__ dw_v,
    ushort* __restrict__ conv_x){
  __shared__ float tile[4096];
  const int d = blockIdx.x;
  const int tid = threadIdx.x;
  const ushort* src = vT + (size_t)d*4096;
  {
    bf16x8 a = *(const bf16x8*)(src + tid*16);
    bf16x8 b = *(const bf16x8*)(src + tid*16 + 8);
#pragma unroll
    for (int j=0;j<8;j++){
      tile[tid*16 + j]     = bf2f((ushort)a[j]);
      tile[tid*16 + 8 + j] = bf2f((ushort)b[j]);
    }
  }
  __syncthreads();
  float wv[9];
#pragma unroll
  for (int i=0;i<9;i++) wv[i] = dw_w[d*9+i];
  const float bias = dw_b[d];
  const float bnsc = dw_g[d] * rsqrtf(dw_v[d] + 1e-5f);
  const float bnb  = dw_bt[d] - dw_m[d]*bnsc;
  ushort* dst = conv_x + (size_t)d*4096;
#pragma unroll 4
  for (int i=0;i<16;i++){
    int p = tid + 256*i;
    int y = p >> 6, x = p & 63;
    float acc = 0.f;
#pragma unroll
    for (int ky=0;ky<3;ky++){
      int yy = y + ky - 1;
      if (yy < 0 || yy > 63) continue;
#pragma unroll
      for (int kx=0;kx<3;kx++){
        int xx = x + kx - 1;
        if (xx < 0 || xx > 63) continue;
        acc += wv[ky*3+kx] * tile[yy*64 + xx];
      }
    }
    float cc = (acc + bias)*bnsc + bnb;
    dst[p] = f2bf(gelu_(cc));
  }
}

// ---------------- K4b: transpose conv_x [512][4096] -> conv_nd [4096][512] -
__global__ __launch_bounds__(256) void k_tr(const ushort* __restrict__ src,
    ushort* __restrict__ dst){
  __shared__ ushort tl[64*72];
  const int tid = threadIdx.x;
  const int n0 = (blockIdx.x & 63) * 64;
  const int d0 = (blockIdx.x >> 6) * 64;
  {
    const int r = tid & 63, ch = tid >> 6;   // r = d-row, ch = n-chunk
    union{ i32x4 q[2]; ushort e[16]; } u;
    const ushort* s = src + (size_t)(d0 + r)*4096 + n0 + ch*16;
    u.q[0] = *(const i32x4*)s;
    u.q[1] = *(const i32x4*)(s + 8);
#pragma unroll
    for (int j=0;j<16;j++) tl[(ch*16 + j)*72 + r] = u.e[j];
  }
  __syncthreads();
  {
    const int nr = tid & 63, dc = tid >> 6;
    i32x4 o0 = *(const i32x4*)&tl[nr*72 + dc*16];
    i32x4 o1 = *(const i32x4*)&tl[nr*72 + dc*16 + 8];
    ushort* dp = dst + (size_t)(n0 + nr)*512 + d0 + dc*16;
    *(i32x4*)dp = o0;
    *(i32x4*)(dp + 8) = o1;
  }
}

// ---------------- K5+K6: spatial (MFMA, blocks 0..63) + channel (block 64) -
__global__ __launch_bounds__(256) void k_sc(const ushort* __restrict__ conv_nd,
    const float* __restrict__ si_w1, const float* __restrict__ si_b1,
    const float* __restrict__ si_g, const float* __restrict__ si_bt,
    const float* __restrict__ si_m, const float* __restrict__ si_v,
    const float* __restrict__ si_w2, const float* __restrict__ si_b2,
    float* __restrict__ sig_sm,
    const float* __restrict__ pooled, const float* __restrict__ ci_w1,
    const float* __restrict__ ci_b1, const float* __restrict__ ci_w2,
    const float* __restrict__ ci_b2, float* __restrict__ sig_cm){
  const int tid = threadIdx.x;
  if (blockIdx.x == 64){
    __shared__ float pl[512];
    __shared__ float h1[128];
    pl[tid]       = pooled[tid]       * (1.0f/4096.0f);
    pl[tid + 256] = pooled[tid + 256] * (1.0f/4096.0f);
    __syncthreads();
    if (tid < 128){
      float acc = ci_b1[tid];
      const float* wr = ci_w1 + (size_t)tid*512;
#pragma unroll 4
      for (int c=0;c<512;c++) acc += wr[c]*pl[c];
      h1[tid] = gelu_(acc);
    }
    __syncthreads();
#pragma unroll
    for (int dd=0; dd<2; dd++){
      int d = tid + 256*dd;
      float acc = ci_b2[d];
      const float* wr = ci_w2 + (size_t)d*128;
#pragma unroll 4
      for (int e=0;e<128;e++) acc += wr[e]*h1[e];
      sig_cm[d] = sigmoid_(acc);
    }
    return;
  }
  // spatial: s1[n][e] = conv_nd[n][:] . w1[e][:]  via MFMA (e = 32)
  const int lane = tid & 63, w = tid >> 6;
  const int l15 = lane & 15, g = lane >> 4;
  const int arow = blockIdx.x*64 + w*16 + l15;
  f32x4 acc[2];
  acc[0] = (f32x4){0.f,0.f,0.f,0.f};
  acc[1] = (f32x4){0.f,0.f,0.f,0.f};
#pragma unroll
  for (int kk=0; kk<16; kk++){
    bf16x8 a = *(const bf16x8*)(conv_nd + (size_t)arow*512 + kk*32 + 8*g);
#pragma unroll
    for (int t=0;t<2;t++){
      bf16x8 b = packf8(si_w1 + (size_t)(16*t + l15)*512 + kk*32 + 8*g);
      acc[t] = __builtin_amdgcn_mfma_f32_16x16x32_bf16(a, b, acc[t], 0,0,0);
    }
  }
  float rowv[4] = {0.f,0.f,0.f,0.f};
#pragma unroll
  for (int t=0;t<2;t++){
    int e = 16*t + l15;
    float s = si_g[e] * rsqrtf(si_v[e] + 1e-5f);
    float b1 = si_b1[e] - si_m[e];
    float bt = si_bt[e];
    float w2e = si_w2[e];
#pragma unroll
    for (int r=0;r<4;r++){
      float v = (acc[t][r] + b1)*s + bt;
      rowv[r] += w2e * gelu_(v);
    }
  }
  float sb2 = si_b2[0];
#pragma unroll
  for (int r=0;r<4;r++){
    float v = rowv[r];
    v += __shfl_xor(v,1); v += __shfl_xor(v,2);
    v += __shfl_xor(v,4); v += __shfl_xor(v,8);
    if (l15 == 0)
      sig_sm[blockIdx.x*64 + w*16 + 4*g + r] = sigmoid_(v + sb2);
  }
}

// ---------------- K8: positional-embed branch: dw3x3 -> gelu -> dw3x3 ------
__global__ __launch_bounds__(256) void k_pe(const float* __restrict__ xin,
    const float* __restrict__ pe_w1, const float* __restrict__ pe_w2,
    float* __restrict__ embed){
  __shared__ float t0[4096];
  __shared__ float t1[4096];
  const int c = blockIdx.x;
  const int tid = threadIdx.x;
  const float* src = xin + (size_t)c*4096;
#pragma unroll
  for (int i=0;i<16;i++) t0[tid + 256*i] = src[tid + 256*i];
  __syncthreads();
  float w1[9], w2[9];
#pragma unroll
  for (int i=0;i<9;i++){ w1[i] = pe_w1[c*9+i]; w2[i] = pe_w2[c*9+i]; }
#pragma unroll 4
  for (int i=0;i<16;i++){
    int p = tid + 256*i;
    int y = p >> 6, x = p & 63;
    float acc = 0.f;
#pragma unroll
    for (int ky=0;ky<3;ky++){
      int yy = y + ky - 1;
      if (yy < 0 || yy > 63) continue;
#pragma unroll
      for (int kx=0;kx<3;kx++){
        int xx = x + kx - 1;
        if (xx < 0 || xx > 63) continue;
        acc += w1[ky*3+kx] * t0[yy*64 + xx];
      }
    }
    t1[p] = gelu_(acc);
  }
  __syncthreads();
  float* dst = embed + (size_t)c*4096;
#pragma unroll 4
  for (int i=0;i<16;i++){
    int p = tid + 256*i;
    int y = p >> 6, x = p & 63;
    float acc = 0.f;
#pragma unroll
    for (int ky=0;ky<3;ky++){
      int yy = y + ky - 1;
      if (yy < 0 || yy > 63) continue;
#pragma unroll
      for (int kx=0;kx<3;kx++){
        int xx = x + kx - 1;
        if (xx < 0 || xx > 63) continue;
        acc += w2[ky*3+kx] * t1[yy*64 + xx];
      }
    }
    dst[p] = acc;
  }
}

// ---------------- K7: gate fuse + output GEMM + embed add -----------------
__global__ __launch_bounds__(64) void k_final(const ushort* __restrict__ att_bf,
    const ushort* __restrict__ conv_nd, const float* __restrict__ sig_sm,
    const float* __restrict__ sig_cm, const float* __restrict__ Wout,
    const float* __restrict__ bout, const float* __restrict__ embed,
    float* __restrict__ out){
  const int lane = threadIdx.x;
  const int l15 = lane & 15, g = lane >> 4;
  const int n0 = blockIdx.x * 16;
  const int rowA = n0 + l15;
  const float srow = sig_sm[rowA];
  f32x4 acc[4];
#pragma unroll
  for (int t=0;t<4;t++) acc[t] = (f32x4){0.f,0.f,0.f,0.f};
#pragma unroll 2
  for (int kk=0;kk<16;kk++){
    int k0 = kk*32;
    bf16x8 at8 = *(const bf16x8*)(att_bf + (size_t)rowA*512 + k0 + 8*g);
    bf16x8 cn8 = *(const bf16x8*)(conv_nd + (size_t)rowA*512 + k0 + 8*g);
    bf16x8 af;
#pragma unroll
    for (int i=0;i<8;i++){
      int d = k0 + 8*g + i;
      float zv = bf2f((ushort)at8[i]) * srow + bf2f((ushort)cn8[i]) * sig_cm[d];
      af[i] = (short)f2bf(zv);
    }
#pragma unroll
    for (int t=0;t<4;t++){
      bf16x8 bf8 = packf8(Wout + (size_t)(16*t+l15)*512 + k0 + 8*g);
      acc[t] = __builtin_amdgcn_mfma_f32_16x16x32_bf16(af, bf8, acc[t], 0,0,0);
    }
  }
#pragma unroll
  for (int t=0;t<4;t++){
    int o = 16*t + l15;
    float bo = bout[o];
#pragma unroll
    for (int r=0;r<4;r++){
      int row = n0 + 4*g + r;
      size_t idx = (size_t)row*64 + o;
      out[idx] = acc[t][r] + bo + embed[idx];
    }
  }
}

extern "C" void kernel_launch(void* const* d_in, const int* in_sizes, int n_in,
                              void* d_out, int out_size, void* d_ws, size_t ws_size,
                              hipStream_t stream){
  (void)in_sizes; (void)n_in; (void)out_size;
  const float* x_in  = (const float*)d_in[0];
  const float* Wq    = (const float*)d_in[1];
  const float* Wk    = (const float*)d_in[2];
  const float* Wv    = (const float*)d_in[3];
  const float* scale = (const float*)d_in[4];
  const float* Wout  = (const float*)d_in[5];
  const float* bout  = (const float*)d_in[6];
  const float* dw_w  = (const float*)d_in[7];
  const float* dw_b  = (const float*)d_in[8];
  const float* dw_g  = (const float*)d_in[9];
  const float* dw_bt = (const float*)d_in[10];
  const float* dw_m  = (const float*)d_in[11];
  const float* dw_v  = (const float*)d_in[12];
  const float* ci_w1 = (const float*)d_in[13];
  const float* ci_b1 = (const float*)d_in[14];
  const float* ci_w2 = (const float*)d_in[15];
  const float* ci_b2 = (const float*)d_in[16];
  const float* si_w1 = (const float*)d_in[17];
  const float* si_b1 = (const float*)d_in[18];
  const float* si_g  = (const float*)d_in[19];
  const float* si_bt = (const float*)d_in[20];
  const float* si_m  = (const float*)d_in[21];
  const float* si_v  = (const float*)d_in[22];
  const float* si_w2 = (const float*)d_in[23];
  const float* si_b2 = (const float*)d_in[24];
  const float* pe_w1 = (const float*)d_in[25];
  const float* pe_w2 = (const float*)d_in[26];
  float* out = (float*)d_out;

  char* p = (char*)d_ws;
  auto alloc = [&](size_t bytes)->char*{
    char* r = p; p += (bytes + 255) & ~(size_t)255; return r;
  };
  ushort* q_bf    = (ushort*)alloc((size_t)4096*512*2);
  ushort* k_bf    = (ushort*)alloc((size_t)4096*512*2);
  ushort* vTb     = (ushort*)alloc((size_t)512*4096*2);
  ushort* att_bf  = (ushort*)alloc((size_t)4096*512*2);
  ushort* conv_x  = (ushort*)alloc((size_t)512*4096*2);
  ushort* conv_nd = (ushort*)alloc((size_t)4096*512*2);
  float*  embed   = (float*) alloc((size_t)64*4096*4);
  float*  lsum_p  = (float*) alloc((size_t)2*8*4096*4);
  float*  pooled  = (float*) alloc(512*4);
  float*  sig_sm  = (float*) alloc(4096*4);
  float*  sig_cm  = (float*) alloc(512*4);
  size_t used = (size_t)(p - (char*)d_ws);
  size_t segBytes = (size_t)4096*512*4 + 256;
  size_t avail = (ws_size > used) ? (ws_size - used) : 0;
  int log2S = (avail >= 2*segBytes) ? 1 : 0;
  int S = 1 << log2S;
  float* O_part = (float*)alloc((size_t)S*segBytes);

  k_qkv<<<dim3(256,3), 256, 0, stream>>>(x_in, Wq, Wk, Wv, scale, q_bf, k_bf, vTb);
  k_attn<<<16*8*S, 256, 0, stream>>>(q_bf, k_bf, vTb, O_part, lsum_p, log2S);
  hipMemsetAsync(pooled, 0, 512*4, stream);
  k_comb<<<256, 256, 0, stream>>>(O_part, lsum_p, att_bf, pooled, S);
  k_conv<<<512, 256, 0, stream>>>(vTb, dw_w, dw_b, dw_g, dw_bt, dw_m, dw_v, conv_x);
  k_tr<<<512, 256, 0, stream>>>(conv_x, conv_nd);
  k_sc<<<65, 256, 0, stream>>>(conv_nd, si_w1, si_b1, si_g, si_bt, si_m, si_v,
                               si_w2, si_b2, sig_sm,
                               pooled, ci_w1, ci_b1, ci_w2, ci_b2, sig_cm);
  k_pe<<<64, 256, 0, stream>>>(x_in, pe_w1, pe_w2, embed);
  k_final<<<256, 64, 0, stream>>>(att_bf, conv_nd, sig_sm, sig_cm, Wout, bout, embed, out);
}